// Round 1
// baseline (1918.264 us; speedup 1.0000x reference)
//
#include <hip/hip_runtime.h>
#include <cstdint>
#include <cstddef>

// CTC-CRF logZ forward (bonito defaults): S=1024 states, NZ=5 transitions.
// alpha_next[s] = LSE(m0+alpha[s], m1+alpha[p], m2+alpha[256+p], m3+alpha[512+p], m4+alpha[768+p]),
//   p = s>>2, m_j = scores[t][n][s*5+j].
// One block per batch element n (32 blocks, 1024 threads, 1 state/thread).
// Pipeline: triple-buffered LDS staging via global_load_lds, counted vmcnt(5),
// raw s_barrier (1 per step). Alpha move-predecessors stored permuted
// ap[p][b]=alpha[256b+p] -> single ds_read_b128; own alpha in a register.

#define NB 32
#define SD 1024
#define CD 5120

__device__ __forceinline__ float fexp2(float x) { return __builtin_amdgcn_exp2f(x); }
__device__ __forceinline__ float flog2(float x) { return __builtin_amdgcn_logf(x); }

__device__ __forceinline__ void gld_lds(const float* g, float* l) {
  __builtin_amdgcn_global_load_lds(
      (const __attribute__((address_space(1))) void*)(const void*)g,
      (__attribute__((address_space(3))) void*)(void*)l, 4, 0, 0);
}

__global__ void __launch_bounds__(1024) ctc_logz(const float* __restrict__ scores,
                                                 float* __restrict__ out, int T) {
  __shared__ float ms[3 * CD];   // 60 KB: staged scores, 3 buffers
  __shared__ float ap[2 * SD];   // 8 KB: permuted alpha, double-buffered
  __shared__ float red[32];

  const int tid = threadIdx.x;
  const int n = blockIdx.x;
  const int lane = tid & 63;
  const int wid = tid >> 6;
  const int wbase = wid << 6;
  const int p4 = (tid >> 2) << 2;                        // p*4
  const int awr = ((tid & 255) << 2) | (tid >> 8);       // ap write slot: p*4 + b

  ap[tid] = 0.f;       // semiring one = 0
  ap[SD + tid] = 0.f;
  float a_cur = 0.f;

  const float K = 1.44269504088896340736f;    // log2(e)
  const float LN2 = 0.69314718055994530942f;  // ln(2)

  const float* gbase = scores + (size_t)n * CD;
  const size_t tstr = (size_t)NB * CD;

  // prologue: issue t=0 -> buf0, t=1 -> buf1 (5 coalesced dword gll per wave each)
  {
    const float* g0 = gbase + tid;
#pragma unroll
    for (int k = 0; k < 5; ++k) gld_lds(g0 + (size_t)k * 1024, &ms[k * 1024 + wbase]);
    if (T > 1) {
      const float* g1 = gbase + tstr + tid;
#pragma unroll
      for (int k = 0; k < 5; ++k) gld_lds(g1 + (size_t)k * 1024, &ms[CD + k * 1024 + wbase]);
    }
  }

  int rb = 0, wb = 2;

  auto compute = [&](int t, int rbv) {
    const float* msr = &ms[rbv * CD + tid * 5];
    const float4 a4 = *(const float4*)&ap[((t + 1) & 1) * SD + p4];  // ds_read_b128
    float m0 = msr[0], m1 = msr[1], m2 = msr[2], m3 = msr[3], m4 = msr[4];
    float t0 = m0 + a_cur;
    float t1 = m1 + a4.x;
    float t2 = m2 + a4.y;
    float t3 = m3 + a4.z;
    float t4 = m4 + a4.w;
    float mx = fmaxf(fmaxf(fmaxf(t0, t1), fmaxf(t2, t3)), t4);
    float nk = -mx * K;
    float s = fexp2(__builtin_fmaf(t0, K, nk));
    s += fexp2(__builtin_fmaf(t1, K, nk));
    s += fexp2(__builtin_fmaf(t2, K, nk));
    s += fexp2(__builtin_fmaf(t3, K, nk));
    s += fexp2(__builtin_fmaf(t4, K, nk));
    a_cur = __builtin_fmaf(flog2(s), LN2, mx);
    ap[(t & 1) * SD + awr] = a_cur;
  };

  int t = 0;
  for (; t < T - 2; ++t) {
    // wait: drains gll(t) (issued 2 iters ago), leaves gll(t+1)'s 5 in flight.
    asm volatile("s_waitcnt vmcnt(5) lgkmcnt(0)\n\ts_barrier" ::: "memory");
    const float* gt = gbase + (size_t)(t + 2) * tstr + tid;
    float* lb = &ms[wb * CD + wbase];
#pragma unroll
    for (int k = 0; k < 5; ++k) gld_lds(gt + (size_t)k * 1024, lb + k * 1024);
    compute(t, rb);
    rb = (rb == 2) ? 0 : rb + 1;
    wb = (wb == 2) ? 0 : wb + 1;
  }
  if (T >= 2) {  // tail t = T-2: no new issue, still one batch in flight
    asm volatile("s_waitcnt vmcnt(5) lgkmcnt(0)\n\ts_barrier" ::: "memory");
    compute(t, rb);
    rb = (rb == 2) ? 0 : rb + 1;
    ++t;
  }
  // tail t = T-1: drain everything
  asm volatile("s_waitcnt vmcnt(0) lgkmcnt(0)\n\ts_barrier" ::: "memory");
  compute(t, rb);

  // final logZ[n] = LSE over all 1024 alpha values (vT = 0)
  float m = a_cur;
#pragma unroll
  for (int d = 1; d < 64; d <<= 1) m = fmaxf(m, __shfl_xor(m, d, 64));
  if (lane == 0) red[wid] = m;
  __syncthreads();
  float bm = red[0];
#pragma unroll
  for (int i = 1; i < 16; ++i) bm = fmaxf(bm, red[i]);
  float e = fexp2((a_cur - bm) * K);
#pragma unroll
  for (int d = 1; d < 64; d <<= 1) e += __shfl_xor(e, d, 64);
  if (lane == 0) red[16 + wid] = e;
  __syncthreads();
  if (tid == 0) {
    float ssum = red[16];
#pragma unroll
    for (int i = 1; i < 16; ++i) ssum += red[16 + i];
    out[n] = __builtin_fmaf(flog2(ssum), LN2, bm);
  }
}

extern "C" void kernel_launch(void* const* d_in, const int* in_sizes, int n_in,
                              void* d_out, int out_size, void* d_ws, size_t ws_size,
                              hipStream_t stream) {
  const float* scores = (const float*)d_in[0];
  float* out = (float*)d_out;
  const long long tot = (long long)in_sizes[0];
  const int T = (int)(tot / ((long long)NB * CD));
  ctc_logz<<<dim3(NB), dim3(1024), 0, stream>>>(scores, out, T);
}

// Round 2
// 762.689 us; speedup vs baseline: 2.5151x; 2.5151x over previous
//
#include <hip/hip_runtime.h>
#include <cstdint>
#include <cstddef>

// CTC-CRF logZ forward: S=1024 states, NZ=5.
// alpha'[s] = LSE(m0+alpha[s], m1+alpha[p], m2+alpha[256+p], m3+alpha[512+p], m4+alpha[768+p]),
//   p = s>>2, m_j = scores[t][n][s*5+j].
// One block per batch element (32 blocks, 1024 threads, 1 state/thread).
// Scores go global->VGPR directly (no sharing between threads): per thread
// dwordx4 + dword at s*20 bytes, software-pipelined 2 steps ahead with 4
// rotating register sets (statically indexed). Only alpha lives in LDS
// (permuted ap[p*4+b] = alpha[256b+p] -> one conflict-free ds_read_b128).
// Raw s_barrier + lgkmcnt(0) only: prefetch loads stay in flight across the
// barrier; compiler inserts counted vmcnt(N) before each set's first use.

#define NB 32
#define SD 1024
#define CD 5120

typedef float f4a __attribute__((ext_vector_type(4), aligned(4)));

__device__ __forceinline__ float fexp2(float x) { return __builtin_amdgcn_exp2f(x); }
__device__ __forceinline__ float flog2(float x) { return __builtin_amdgcn_logf(x); }

__global__ void __launch_bounds__(1024) ctc_logz(const float* __restrict__ scores,
                                                 float* __restrict__ out, int T) {
  __shared__ float ap[2 * SD];   // permuted alpha, double-buffered
  __shared__ float red[32];

  const int tid = threadIdx.x;
  const int n = blockIdx.x;
  const int lane = tid & 63;
  const int wid = tid >> 6;
  const int p4 = (tid >> 2) << 2;                   // predecessor chunk base
  const int awr = ((tid & 255) << 2) | (tid >> 8);  // ap slot: p*4 + b

  ap[tid] = 0.f;
  ap[SD + tid] = 0.f;
  float a_cur = 0.f;

  const float K = 1.44269504088896340736f;    // log2(e)
  const float LN2 = 0.69314718055994530942f;  // ln(2)

  const float* sn = scores + (size_t)n * CD + (size_t)tid * 5;
  const size_t tstr = (size_t)NB * CD;

  auto LD = [&](int tt, f4a& qa, float& qb) {
    const float* p = sn + (size_t)(tt < T ? tt : T - 1) * tstr;  // uniform clamp
    qa = *(const f4a*)p;   // global_load_dwordx4 (4B-aligned ok)
    qb = p[4];             // global_load_dword offset:16
  };

  auto CP = [&](int t, const f4a& qa, float qb) {
    const f4a av = *(const f4a*)&ap[((t + 1) & 1) * SD + p4];  // ds_read_b128
    float t0 = qa.x + a_cur;   // stay
    float t1 = qa.y + av.x;    // alpha[p]
    float t2 = qa.z + av.y;    // alpha[256+p]
    float t3 = qa.w + av.z;    // alpha[512+p]
    float t4 = qb + av.w;      // alpha[768+p]
    float mx = fmaxf(fmaxf(fmaxf(t0, t1), fmaxf(t2, t3)), t4);
    float nk = -mx * K;
    float s = fexp2(__builtin_fmaf(t0, K, nk));
    s += fexp2(__builtin_fmaf(t1, K, nk));
    s += fexp2(__builtin_fmaf(t2, K, nk));
    s += fexp2(__builtin_fmaf(t3, K, nk));
    s += fexp2(__builtin_fmaf(t4, K, nk));
    a_cur = __builtin_fmaf(flog2(s), LN2, mx);
    ap[(t & 1) * SD + awr] = a_cur;
    // drain only LDS (alpha write) before the barrier; global prefetches stay
    // in flight (raw s_barrier, NOT __syncthreads -> no vmcnt(0) drain).
    asm volatile("s_waitcnt lgkmcnt(0)\n\ts_barrier" ::: "memory");
  };

  f4a qa0, qa1, qa2, qa3;
  float qb0, qb1, qb2, qb3;
  LD(0, qa0, qb0);
  LD(1, qa1, qb1);
  __syncthreads();  // ap zeros visible

  int t = 0;
  const int T4 = T & ~3;
  for (; t < T4; t += 4) {
    LD(t + 2, qa2, qb2); CP(t,     qa0, qb0);
    LD(t + 3, qa3, qb3); CP(t + 1, qa1, qb1);
    LD(t + 4, qa0, qb0); CP(t + 2, qa2, qb2);
    LD(t + 5, qa1, qb1); CP(t + 3, qa3, qb3);
  }
  // generic remainder (not taken for T=2000): sets 0,1 hold T4, T4+1
  if (t < T) { CP(t, qa0, qb0); ++t; }
  if (t < T) { CP(t, qa1, qb1); ++t; }
  if (t < T) { LD(t, qa2, qb2); CP(t, qa2, qb2); ++t; }
  if (t < T) { LD(t, qa3, qb3); CP(t, qa3, qb3); }

  // logZ[n] = LSE over all 1024 alpha (vT = 0)
  float m = a_cur;
#pragma unroll
  for (int d = 1; d < 64; d <<= 1) m = fmaxf(m, __shfl_xor(m, d, 64));
  if (lane == 0) red[wid] = m;
  __syncthreads();
  float bm = red[0];
#pragma unroll
  for (int i = 1; i < 16; ++i) bm = fmaxf(bm, red[i]);
  float e = fexp2((a_cur - bm) * K);
#pragma unroll
  for (int d = 1; d < 64; d <<= 1) e += __shfl_xor(e, d, 64);
  if (lane == 0) red[16 + wid] = e;
  __syncthreads();
  if (tid == 0) {
    float ssum = red[16];
#pragma unroll
    for (int i = 1; i < 16; ++i) ssum += red[16 + i];
    out[n] = __builtin_fmaf(flog2(ssum), LN2, bm);
  }
}

extern "C" void kernel_launch(void* const* d_in, const int* in_sizes, int n_in,
                              void* d_out, int out_size, void* d_ws, size_t ws_size,
                              hipStream_t stream) {
  const float* scores = (const float*)d_in[0];
  float* out = (float*)d_out;
  const long long tot = (long long)in_sizes[0];
  const int T = (int)(tot / ((long long)NB * CD));
  ctc_logz<<<dim3(NB), dim3(1024), 0, stream>>>(scores, out, T);
}